// Round 7
// baseline (200.300 us; speedup 1.0000x reference)
//
#include <hip/hip_runtime.h>
#include <hip/hip_bf16.h>

// IN_DIM=128, H=8, D=16, H*D=128.

typedef short short8 __attribute__((ext_vector_type(8)));
typedef float f32x4 __attribute__((ext_vector_type(4)));

__device__ __forceinline__ unsigned pack_bf16(float a, float b) {
    unsigned ua = __float_as_uint(a), ub = __float_as_uint(b);
    ua += 0x7fffu + ((ua >> 16) & 1u);          // RNE round to bf16
    ub += 0x7fffu + ((ub >> 16) & 1u);
    return (ua >> 16) | (ub & 0xffff0000u);
}

#define ULO(u) __uint_as_float((u) << 16)
#define UHI(u) __uint_as_float((u) & 0xffff0000u)

// ---------------------------------------------------------------------------
// prep_all: three independent jobs partitioned by blockIdx:
//   [0,24):            prep_w  -> swizzled bf16 WT images (32KB each)
//   [24,24+hB):        prep_h  -> swizzled bf16 h image (256B/row, padded)
//   [24+hB, ...):      zero counts
// ---------------------------------------------------------------------------
__global__ __launch_bounds__(256) void prep_all(
    const float* __restrict__ W0, const float* __restrict__ W1,
    const float* __restrict__ W2, const float* __restrict__ h,
    unsigned char* __restrict__ WTb, unsigned char* __restrict__ hb,
    int* __restrict__ counts, int n, int hB)
{
    const int b = blockIdx.x;
    if (b < 24) {
        const int w   = b >> 3;
        const int idx = (b & 7) * 256 + threadIdx.x;          // [0, 2048)
        const float* W = (w == 0) ? W0 : (w == 1) ? W1 : W2;
        unsigned char* wt = WTb + w * 32768;
        const int kp = idx >> 5;           // k-pair (2kp,2kp+1), [0,64)
        const int c4 = (idx & 31) * 4;     // col group
        const float* Wp = W + (size_t)(2 * kp) * 128 + c4;
        float4 wa = *(const float4*)Wp;
        float4 wb = *(const float4*)(Wp + 128);
        float a0[4] = {wa.x, wa.y, wa.z, wa.w};
        float a1[4] = {wb.x, wb.y, wb.z, wb.w};
#pragma unroll
        for (int i = 0; i < 4; ++i) {
            const int col = c4 + i;
            *(unsigned*)(wt + col * 256 + ((4 * kp) ^ ((col & 7) << 4))) =
                pack_bf16(a0[i], a1[i]);
        }
    } else if (b < 24 + hB) {
        const int idx = (b - 24) * 256 + threadIdx.x;          // [0, npad*32)
        const int row = idx >> 5;
        const int c4  = (idx & 31) * 4;
        float4 v = make_float4(0.f, 0.f, 0.f, 0.f);
        if (row < n) v = *(const float4*)(h + (size_t)row * 128 + c4);
        *(uint2*)(hb + row * 256 + ((c4 * 2) ^ ((row & 7) << 4))) =
            make_uint2(pack_bf16(v.x, v.y), pack_bf16(v.z, v.w));
    } else {
        const int i = (b - 24 - hB) * 256 + threadIdx.x;
        if (i < n) counts[i] = 0;
    }
}

// ---------------------------------------------------------------------------
// CSR build
// ---------------------------------------------------------------------------
__global__ void hist_kernel(const int* __restrict__ dst, int* __restrict__ counts, int e) {
    int i = blockIdx.x * blockDim.x + threadIdx.x;
    if (i < e) atomicAdd(&counts[dst[i]], 1);
}

__global__ void scan_block_sums(const int* __restrict__ counts, int* __restrict__ bsums, int nelem) {
    __shared__ int red[4];
    int i = blockIdx.x * 256 + threadIdx.x;
    int v = (i < nelem) ? counts[i] : 0;
#pragma unroll
    for (int o = 32; o > 0; o >>= 1) v += __shfl_down(v, o, 64);
    if ((threadIdx.x & 63) == 0) red[threadIdx.x >> 6] = v;
    __syncthreads();
    if (threadIdx.x == 0) bsums[blockIdx.x] = red[0] + red[1] + red[2] + red[3];
}

// scan_final2: computes its own exclusive prefix of bsums (nb<=256: one
// element per thread + block reduce), then block-scans counts and writes
// offsets + cur (fill's atomic cursor copy). offsets[nelem]=e written by the
// thread with i==nelem.
__global__ void scan_final2(const int* __restrict__ counts, const int* __restrict__ bsums,
                            int* __restrict__ offsets, int* __restrict__ cur,
                            int nelem, int e) {
    __shared__ int tmp[256];
    __shared__ int red[4];
    const int t = threadIdx.x;

    int pre = (t < blockIdx.x) ? bsums[t] : 0;   // bsums index == t, valid: nb<=256
#pragma unroll
    for (int o = 32; o > 0; o >>= 1) pre += __shfl_down(pre, o, 64);
    if ((t & 63) == 0) red[t >> 6] = pre;
    __syncthreads();
    const int base = red[0] + red[1] + red[2] + red[3];

    const int i = blockIdx.x * 256 + t;
    int v = (i < nelem) ? counts[i] : 0;
    tmp[t] = v;
    __syncthreads();
    for (int o = 1; o < 256; o <<= 1) {
        int u = (t >= o) ? tmp[t - o] : 0;
        __syncthreads();
        tmp[t] += u;
        __syncthreads();
    }
    if (i < nelem) {
        const int ofs = base + tmp[t] - v;
        offsets[i] = ofs;
        cur[i] = ofs;
    }
    if (i == nelem) offsets[nelem] = e;
}

// ---------------------------------------------------------------------------
// gemm_fill: fused independent work.
//   blocks [0,nblk):  MFMA QKV GEMM (BM=64, 8 waves 2x4, 32x32/wave).
//   blocks [nblk,..): edge fill (scatter srcSorted via cur atomics).
// Outputs (bf16 pairs): Qb[row][64] uints; KVb[row][128] uints
// (even uint c = K cols (c,c+1), odd = V cols (c-1,c)).
// ---------------------------------------------------------------------------
__global__ __launch_bounds__(512) void gemm_fill(
    const unsigned char* __restrict__ hb, const unsigned char* __restrict__ WTb,
    const float* __restrict__ b0, const float* __restrict__ b1,
    const float* __restrict__ b2,
    unsigned* __restrict__ qb, unsigned* __restrict__ kvU,
    const int* __restrict__ src, const int* __restrict__ dst,
    int* __restrict__ cur, int* __restrict__ srcSorted,
    int nblk, int e)
{
    __shared__ __align__(16) unsigned char lds[49152];  // [0,16K): h  [16K,48K): WT
    const int tid = threadIdx.x;

    if (blockIdx.x >= nblk) {      // ---- fill part ----
        const int i = (blockIdx.x - nblk) * 512 + tid;
        if (i < e) {
            int pos = atomicAdd(&cur[dst[i]], 1);
            srcSorted[pos] = src[i];
        }
        return;
    }

    // ---- GEMM part ----
    const int row0 = blockIdx.x * 64;
    {
        const uint4* s = (const uint4*)(hb + (size_t)row0 * 256);
        uint4* d = (uint4*)lds;
        d[tid]       = s[tid];
        d[tid + 512] = s[tid + 512];
    }

    const float* bs[3] = {b0, b1, b2};
    const int lane = tid & 63, wave = tid >> 6;
    const int wr = wave >> 2, wc = wave & 3;       // 2x4 wave grid
    const int lr = lane & 15, lg = lane >> 4;

    for (int w = 0; w < 3; ++w) {
        __syncthreads();
        {   // stage WT: 32KB memcpy
            const uint4* s = (const uint4*)(WTb + w * 32768);
            uint4* d = (uint4*)(lds + 16384);
#pragma unroll
            for (int t = 0; t < 4; ++t) d[tid + t * 512] = s[tid + t * 512];
        }
        __syncthreads();

        f32x4 acc[2][2];
#pragma unroll
        for (int nt = 0; nt < 2; ++nt) {
            const float bv = bs[w][wc * 32 + nt * 16 + lr];
            acc[0][nt] = (f32x4){bv, bv, bv, bv};
            acc[1][nt] = (f32x4){bv, bv, bv, bv};
        }
#pragma unroll
        for (int ks = 0; ks < 4; ++ks) {
            const int kb = ks * 64 + lg * 16;
            short8 af[2], bf[2];
#pragma unroll
            for (int mt = 0; mt < 2; ++mt) {
                const int row = wr * 32 + mt * 16 + lr;
                af[mt] = *(const short8*)(lds + row * 256 + (kb ^ ((row & 7) << 4)));
            }
#pragma unroll
            for (int nt = 0; nt < 2; ++nt) {
                const int col = wc * 32 + nt * 16 + lr;
                bf[nt] = *(const short8*)(lds + 16384 + col * 256 + (kb ^ ((col & 7) << 4)));
            }
#pragma unroll
            for (int mt = 0; mt < 2; ++mt)
#pragma unroll
                for (int nt = 0; nt < 2; ++nt)
                    acc[mt][nt] = __builtin_amdgcn_mfma_f32_16x16x32_bf16(
                        af[mt], bf[nt], acc[mt][nt], 0, 0, 0);
        }

#pragma unroll
        for (int mt = 0; mt < 2; ++mt) {
#pragma unroll
            for (int nt = 0; nt < 2; ++nt) {
                const int col = wc * 32 + nt * 16 + lr;
#pragma unroll
                for (int r = 0; r < 4; ++r) {
                    const int row = row0 + wr * 32 + mt * 16 + lg * 4 + r;
                    const float v  = acc[mt][nt][r];
                    const float vn = __shfl_xor(v, 1);
                    if (!(lane & 1)) {
                        const unsigned u = pack_bf16(v, vn);
                        if (w == 0)      qb[(size_t)row * 64 + (col >> 1)] = u;
                        else if (w == 1) kvU[(size_t)row * 128 + col] = u;
                        else             kvU[(size_t)row * 128 + col + 1] = u;
                    }
                }
            }
        }
    }
}

// ---------------------------------------------------------------------------
// Gather: one wave per node; lane l owns dims {2l,2l+1}; head = l>>3.
// Per edge: one uint2 (bf16 K pair + V pair), in-pair dot, 3-step 8-lane
// shuffle reduce, exp, 2 fma. Scores clamped to [-5,5] before softmax ->
// segment-max shift unnecessary (shift invariance).
// ---------------------------------------------------------------------------
__global__ __launch_bounds__(256) void mha_node(
    const unsigned* __restrict__ Qb, const uint2* __restrict__ KV,
    const int* __restrict__ offsets, const int* __restrict__ srcSorted,
    float* __restrict__ out, int n)
{
    const int lane = threadIdx.x & 63;
    const int node = (blockIdx.x * blockDim.x + threadIdx.x) >> 6;
    if (node >= n) return;

    const unsigned qu = Qb[(size_t)node * 64 + lane];
    const float qx = ULO(qu), qy = UHI(qu);
    const int beg = offsets[node], end = offsets[node + 1];

    float accx = 0.f, accy = 0.f, lsum = 0.f;

#define EDGE_COMPUTE(kv)                                              \
    {                                                                 \
        float prod = fmaf(ULO((kv).x), qx, UHI((kv).x) * qy);         \
        prod += __shfl_xor(prod, 1);                                  \
        prod += __shfl_xor(prod, 2);                                  \
        prod += __shfl_xor(prod, 4);                                  \
        float sc = fminf(5.f, fmaxf(-5.f, prod * 0.25f));             \
        float p = __expf(sc);                                         \
        lsum += p;                                                    \
        accx = fmaf(p, ULO((kv).y), accx);                            \
        accy = fmaf(p, UHI((kv).y), accy);                            \
    }

    for (int j0 = beg; j0 < end; j0 += 64) {
        const int rem = end - j0;
        const int cnt = rem < 64 ? rem : 64;
        int myS = (lane < cnt) ? srcSorted[j0 + lane] : 0;

        int t = 0;
        for (; t + 8 <= cnt; t += 8) {
            uint2 kv[8];
#pragma unroll
            for (int u = 0; u < 8; ++u) {
                int s = __shfl(myS, t + u);
                kv[u] = KV[(size_t)s * 64 + lane];
            }
#pragma unroll
            for (int u = 0; u < 8; ++u) EDGE_COMPUTE(kv[u]);
        }
        for (; t < cnt; ++t) {
            int s = __shfl(myS, t);
            uint2 kv0 = KV[(size_t)s * 64 + lane];
            EDGE_COMPUTE(kv0);
        }
    }

    float inv = (lsum > 0.f) ? 1.f / lsum : 0.f;
    *(float2*)(out + (size_t)node * 128 + lane * 2) =
        make_float2(accx * inv, accy * inv);
}

// ---------------------------------------------------------------------------
extern "C" void kernel_launch(void* const* d_in, const int* in_sizes, int n_in,
                              void* d_out, int out_size, void* d_ws, size_t ws_size,
                              hipStream_t stream) {
    const float* h  = (const float*)d_in[0];
    const float* Wq = (const float*)d_in[1];
    const float* bq = (const float*)d_in[2];
    const float* Wk = (const float*)d_in[3];
    const float* bk = (const float*)d_in[4];
    const float* Wv = (const float*)d_in[5];
    const float* bv = (const float*)d_in[6];
    const int*   src = (const int*)d_in[7];
    const int*   dst = (const int*)d_in[8];
    float* out = (float*)d_out;

    const int n = in_sizes[0] / 128;
    const int e = in_sizes[7];
    const int nblk = (n + 63) / 64;        // GEMM blocks
    const int npad = nblk * 64;            // padded rows
    const int nb = (n + 255) / 256;        // scan blocks (<=256; n=50000 -> 196)
    const int hB = npad / 8;               // prep_h blocks (npad*32/256)
    const int zB = nb;                     // counts-zero blocks
    const int fB = (e + 511) / 512;        // fill blocks

    char* ws = (char*)d_ws;
    size_t off = 0;
    auto alloc = [&](size_t bytes) {
        char* p = ws + off;
        off = (off + bytes + 255) & ~(size_t)255;
        return p;
    };
    unsigned char* hb   = (unsigned char*)alloc((size_t)npad * 256);
    unsigned char* WTb  = (unsigned char*)alloc(3 * 32768);
    unsigned* Qb        = (unsigned*)alloc((size_t)npad * 64 * 4);
    unsigned* KVb       = (unsigned*)alloc((size_t)npad * 128 * 4);
    int* counts         = (int*)alloc((size_t)n * sizeof(int));
    int* offsets        = (int*)alloc((size_t)(n + 1) * sizeof(int));
    int* cur            = (int*)alloc((size_t)n * sizeof(int));
    int* bsums          = (int*)alloc((size_t)nb * sizeof(int));
    int* srcSorted      = (int*)alloc((size_t)e * sizeof(int));
    (void)ws_size; (void)n_in; (void)out_size;

    prep_all<<<24 + hB + zB, 256, 0, stream>>>(Wq, Wk, Wv, h, WTb, hb, counts, n, hB);
    hist_kernel<<<(e + 255) / 256, 256, 0, stream>>>(dst, counts, e);
    scan_block_sums<<<nb, 256, 0, stream>>>(counts, bsums, n);
    scan_final2<<<nb, 256, 0, stream>>>(counts, bsums, offsets, cur, n, e);
    gemm_fill<<<nblk + fB, 512, 0, stream>>>(hb, WTb, bq, bk, bv, Qb, KVb,
                                             src, dst, cur, srcSorted, nblk, e);
    mha_node<<<((size_t)n * 64 + 255) / 256, 256, 0, stream>>>(
        Qb, (const uint2*)KVb, offsets, srcSorted, out, n);
}

// Round 8
// 147.356 us; speedup vs baseline: 1.3593x; 1.3593x over previous
//
#include <hip/hip_runtime.h>
#include <hip/hip_bf16.h>

// IN_DIM=128, H=8, D=16, H*D=128.

typedef short short8 __attribute__((ext_vector_type(8)));
typedef float f32x4 __attribute__((ext_vector_type(4)));

__device__ __forceinline__ unsigned pack_bf16(float a, float b) {
    unsigned ua = __float_as_uint(a), ub = __float_as_uint(b);
    ua += 0x7fffu + ((ua >> 16) & 1u);          // RNE round to bf16
    ub += 0x7fffu + ((ub >> 16) & 1u);
    return (ua >> 16) | (ub & 0xffff0000u);
}

#define ULO(u) __uint_as_float((u) << 16)
#define UHI(u) __uint_as_float((u) & 0xffff0000u)

// ---------------------------------------------------------------------------
// prep_all: three independent jobs partitioned by blockIdx:
//   [0,24):        prep_w -> swizzled bf16 WT images (32KB each)
//   [24,24+hB):    prep_h -> swizzled bf16 h image (256B/row, zero-padded)
//   [24+hB,...):   zero counts
// ---------------------------------------------------------------------------
__global__ __launch_bounds__(256) void prep_all(
    const float* __restrict__ W0, const float* __restrict__ W1,
    const float* __restrict__ W2, const float* __restrict__ h,
    unsigned char* __restrict__ WTb, unsigned char* __restrict__ hb,
    int* __restrict__ counts, int n, int hB)
{
    const int b = blockIdx.x;
    if (b < 24) {
        const int w   = b >> 3;
        const int idx = (b & 7) * 256 + threadIdx.x;          // [0, 2048)
        const float* W = (w == 0) ? W0 : (w == 1) ? W1 : W2;
        unsigned char* wt = WTb + w * 32768;
        const int kp = idx >> 5;           // k-pair (2kp,2kp+1), [0,64)
        const int c4 = (idx & 31) * 4;     // col group
        const float* Wp = W + (size_t)(2 * kp) * 128 + c4;
        float4 wa = *(const float4*)Wp;
        float4 wb = *(const float4*)(Wp + 128);
        float a0[4] = {wa.x, wa.y, wa.z, wa.w};
        float a1[4] = {wb.x, wb.y, wb.z, wb.w};
#pragma unroll
        for (int i = 0; i < 4; ++i) {
            const int col = c4 + i;
            *(unsigned*)(wt + col * 256 + ((4 * kp) ^ ((col & 7) << 4))) =
                pack_bf16(a0[i], a1[i]);
        }
    } else if (b < 24 + hB) {
        const int idx = (b - 24) * 256 + threadIdx.x;          // [0, npad*32)
        const int row = idx >> 5;
        const int c4  = (idx & 31) * 4;
        float4 v = make_float4(0.f, 0.f, 0.f, 0.f);
        if (row < n) v = *(const float4*)(h + (size_t)row * 128 + c4);
        *(uint2*)(hb + row * 256 + ((c4 * 2) ^ ((row & 7) << 4))) =
            make_uint2(pack_bf16(v.x, v.y), pack_bf16(v.z, v.w));
    } else {
        const int i = (b - 24 - hB) * 256 + threadIdx.x;
        if (i < n) counts[i] = 0;
    }
}

// ---------------------------------------------------------------------------
// CSR build. hist_rank: histogram AND per-edge rank (the atomicAdd return) so
// the later fill needs no atomics.
// ---------------------------------------------------------------------------
__global__ void hist_rank(const int* __restrict__ dst, int* __restrict__ counts,
                          int* __restrict__ rank, int e) {
    int i = blockIdx.x * blockDim.x + threadIdx.x;
    if (i < e) rank[i] = atomicAdd(&counts[dst[i]], 1);
}

__global__ void scan_block_sums(const int* __restrict__ counts, int* __restrict__ bsums, int nelem) {
    __shared__ int red[4];
    int i = blockIdx.x * 256 + threadIdx.x;
    int v = (i < nelem) ? counts[i] : 0;
#pragma unroll
    for (int o = 32; o > 0; o >>= 1) v += __shfl_down(v, o, 64);
    if ((threadIdx.x & 63) == 0) red[threadIdx.x >> 6] = v;
    __syncthreads();
    if (threadIdx.x == 0) bsums[blockIdx.x] = red[0] + red[1] + red[2] + red[3];
}

// scan_final2: computes its own exclusive prefix of bsums (nb<=256), then
// block-scans counts and writes offsets. offsets[nelem]=e by thread i==nelem.
__global__ void scan_final2(const int* __restrict__ counts, const int* __restrict__ bsums,
                            int* __restrict__ offsets, int nelem, int e) {
    __shared__ int tmp[256];
    __shared__ int red[4];
    const int t = threadIdx.x;

    int pre = (t < blockIdx.x) ? bsums[t] : 0;
#pragma unroll
    for (int o = 32; o > 0; o >>= 1) pre += __shfl_down(pre, o, 64);
    if ((t & 63) == 0) red[t >> 6] = pre;
    __syncthreads();
    const int base = red[0] + red[1] + red[2] + red[3];

    const int i = blockIdx.x * 256 + t;
    int v = (i < nelem) ? counts[i] : 0;
    tmp[t] = v;
    __syncthreads();
    for (int o = 1; o < 256; o <<= 1) {
        int u = (t >= o) ? tmp[t - o] : 0;
        __syncthreads();
        tmp[t] += u;
        __syncthreads();
    }
    if (i < nelem) offsets[i] = base + tmp[t] - v;
    if (i == nelem) offsets[nelem] = e;
}

// fill: no atomics — position comes from offsets[dst] + rank.
__global__ void fill_kernel(const int* __restrict__ src, const int* __restrict__ dst,
                            const int* __restrict__ rank, const int* __restrict__ offsets,
                            int* __restrict__ srcSorted, int e) {
    int i = blockIdx.x * blockDim.x + threadIdx.x;
    if (i < e) srcSorted[offsets[dst[i]] + rank[i]] = src[i];
}

// ---------------------------------------------------------------------------
// MFMA QKV GEMM. BM=64 rows/block, 512 threads = 8 waves (2x4); each wave a
// 32x32 tile = 2x2 frags of mfma_f32_16x16x32_bf16, K-loop 4 steps.
// Staging = raw uint4 memcpy from prebuilt bf16 images. LDS 48KB.
// Epilogue: packed bf16-pair uints staged into the (free) WT LDS region,
// then coalesced uint4 row writes to the per-W plane.
// Planes: Qb/Kb/Vb each [row][64] uints; uint c = cols (2c,2c+1).
// ---------------------------------------------------------------------------
__global__ __launch_bounds__(512) void qkv_gemm_mfma(
    const unsigned char* __restrict__ hb, const unsigned char* __restrict__ WTb,
    const float* __restrict__ b0, const float* __restrict__ b1,
    const float* __restrict__ b2,
    unsigned* __restrict__ qb, unsigned* __restrict__ kb, unsigned* __restrict__ vb)
{
    __shared__ __align__(16) unsigned char lds[49152];  // [0,16K): h  [16K,48K): WT/epi
    const int tid  = threadIdx.x;
    const int row0 = blockIdx.x * 64;

    {   // stage h tile: 16KB memcpy
        const uint4* s = (const uint4*)(hb + (size_t)row0 * 256);
        uint4* d = (uint4*)lds;
        d[tid]       = s[tid];
        d[tid + 512] = s[tid + 512];
    }

    const float* bs[3] = {b0, b1, b2};
    unsigned* planes[3] = {qb, kb, vb};

    const int lane = tid & 63, wave = tid >> 6;
    const int wr = wave >> 2, wc = wave & 3;       // 2x4 wave grid
    const int lr = lane & 15, lg = lane >> 4;

    for (int w = 0; w < 3; ++w) {
        __syncthreads();   // prev copy-out done / h-stage done (first iter)
        {   // stage WT: 32KB memcpy
            const uint4* s = (const uint4*)(WTb + w * 32768);
            uint4* d = (uint4*)(lds + 16384);
#pragma unroll
            for (int t = 0; t < 4; ++t) d[tid + t * 512] = s[tid + t * 512];
        }
        __syncthreads();

        f32x4 acc[2][2];
#pragma unroll
        for (int nt = 0; nt < 2; ++nt) {
            const float bv = bs[w][wc * 32 + nt * 16 + lr];
            acc[0][nt] = (f32x4){bv, bv, bv, bv};
            acc[1][nt] = (f32x4){bv, bv, bv, bv};
        }
#pragma unroll
        for (int ks = 0; ks < 4; ++ks) {
            const int kbyte = ks * 64 + lg * 16;
            short8 af[2], bf[2];
#pragma unroll
            for (int mt = 0; mt < 2; ++mt) {
                const int row = wr * 32 + mt * 16 + lr;
                af[mt] = *(const short8*)(lds + row * 256 + (kbyte ^ ((row & 7) << 4)));
            }
#pragma unroll
            for (int nt = 0; nt < 2; ++nt) {
                const int col = wc * 32 + nt * 16 + lr;
                bf[nt] = *(const short8*)(lds + 16384 + col * 256 + (kbyte ^ ((col & 7) << 4)));
            }
#pragma unroll
            for (int mt = 0; mt < 2; ++mt)
#pragma unroll
                for (int nt = 0; nt < 2; ++nt)
                    acc[mt][nt] = __builtin_amdgcn_mfma_f32_16x16x32_bf16(
                        af[mt], bf[nt], acc[mt][nt], 0, 0, 0);
        }

        __syncthreads();   // all waves done reading WT; region becomes epi scratch
        {   // epi: even lanes write packed pair -> [row][colpair] (64x64 uints)
            unsigned* epi = (unsigned*)(lds + 16384);
#pragma unroll
            for (int mt = 0; mt < 2; ++mt)
#pragma unroll
                for (int nt = 0; nt < 2; ++nt) {
                    const int col = wc * 32 + nt * 16 + lr;
#pragma unroll
                    for (int r = 0; r < 4; ++r) {
                        const int row = wr * 32 + mt * 16 + lg * 4 + r;
                        const float v  = acc[mt][nt][r];
                        const float vn = __shfl_xor(v, 1);
                        if (!(lane & 1)) epi[row * 64 + (col >> 1)] = pack_bf16(v, vn);
                    }
                }
        }
        __syncthreads();
        {   // coalesced copy-out: 1024 uint4 = 64 rows x 256B
            const uint4* s = (const uint4*)(lds + 16384);
            uint4* d = (uint4*)(planes[w] + (size_t)row0 * 64);
            d[tid]       = s[tid];
            d[tid + 512] = s[tid + 512];
        }
    }
}

// ---------------------------------------------------------------------------
// Gather: one wave per node; lane l owns dims {2l,2l+1}; head = l>>3.
// Per edge: two 4B gathers (bf16 K pair, V pair), in-pair dot, 3-step 8-lane
// shuffle reduce, exp, 2 fma. Scores clamped to [-5,5] before softmax ->
// segment-max shift unnecessary (shift invariance). 0.25 scale folded into q.
// ---------------------------------------------------------------------------
__global__ __launch_bounds__(256) void mha_node(
    const unsigned* __restrict__ Qb, const unsigned* __restrict__ Kb,
    const unsigned* __restrict__ Vb,
    const int* __restrict__ offsets, const int* __restrict__ srcSorted,
    float* __restrict__ out, int n)
{
    const int lane = threadIdx.x & 63;
    const int node = (blockIdx.x * blockDim.x + threadIdx.x) >> 6;
    if (node >= n) return;

    const unsigned qu = Qb[(size_t)node * 64 + lane];
    const float qx = ULO(qu) * 0.25f, qy = UHI(qu) * 0.25f;
    const int beg = offsets[node], end = offsets[node + 1];

    float accx = 0.f, accy = 0.f, lsum = 0.f;

#define EDGE_COMPUTE(ku, vu)                                          \
    {                                                                 \
        float prod = fmaf(ULO(ku), qx, UHI(ku) * qy);                 \
        prod += __shfl_xor(prod, 1);                                  \
        prod += __shfl_xor(prod, 2);                                  \
        prod += __shfl_xor(prod, 4);                                  \
        float sc = fminf(5.f, fmaxf(-5.f, prod));                     \
        float p = __expf(sc);                                         \
        lsum += p;                                                    \
        accx = fmaf(p, ULO(vu), accx);                                \
        accy = fmaf(p, UHI(vu), accy);                                \
    }

    for (int j0 = beg; j0 < end; j0 += 64) {
        const int rem = end - j0;
        const int cnt = rem < 64 ? rem : 64;
        int myS = (lane < cnt) ? srcSorted[j0 + lane] : 0;

        int t = 0;
        for (; t + 8 <= cnt; t += 8) {
            unsigned ku[8], vu[8];
#pragma unroll
            for (int u = 0; u < 8; ++u) {
                int s = __shfl(myS, t + u);
                ku[u] = Kb[(size_t)s * 64 + lane];
                vu[u] = Vb[(size_t)s * 64 + lane];
            }
#pragma unroll
            for (int u = 0; u < 8; ++u) EDGE_COMPUTE(ku[u], vu[u]);
        }
        for (; t < cnt; ++t) {
            int s = __shfl(myS, t);
            unsigned ku0 = Kb[(size_t)s * 64 + lane];
            unsigned vu0 = Vb[(size_t)s * 64 + lane];
            EDGE_COMPUTE(ku0, vu0);
        }
    }

    float inv = (lsum > 0.f) ? 1.f / lsum : 0.f;
    *(float2*)(out + (size_t)node * 128 + lane * 2) =
        make_float2(accx * inv, accy * inv);
}

// ---------------------------------------------------------------------------
extern "C" void kernel_launch(void* const* d_in, const int* in_sizes, int n_in,
                              void* d_out, int out_size, void* d_ws, size_t ws_size,
                              hipStream_t stream) {
    const float* h  = (const float*)d_in[0];
    const float* Wq = (const float*)d_in[1];
    const float* bq = (const float*)d_in[2];
    const float* Wk = (const float*)d_in[3];
    const float* bk = (const float*)d_in[4];
    const float* Wv = (const float*)d_in[5];
    const float* bv = (const float*)d_in[6];
    const int*   src = (const int*)d_in[7];
    const int*   dst = (const int*)d_in[8];
    float* out = (float*)d_out;

    const int n = in_sizes[0] / 128;
    const int e = in_sizes[7];
    const int nblk = (n + 63) / 64;        // GEMM blocks
    const int npad = nblk * 64;            // padded rows
    const int nb = (n + 255) / 256;        // scan blocks (<=256; n=50000 -> 196)
    const int hB = npad / 8;               // prep_h blocks
    const int zB = nb;                     // counts-zero blocks

    char* ws = (char*)d_ws;
    size_t off = 0;
    auto alloc = [&](size_t bytes) {
        char* p = ws + off;
        off = (off + bytes + 255) & ~(size_t)255;
        return p;
    };
    unsigned char* hb  = (unsigned char*)alloc((size_t)npad * 256);
    unsigned char* WTb = (unsigned char*)alloc(3 * 32768);
    unsigned* Qb       = (unsigned*)alloc((size_t)npad * 64 * 4);
    unsigned* Kb       = (unsigned*)alloc((size_t)npad * 64 * 4);
    unsigned* Vb       = (unsigned*)alloc((size_t)npad * 64 * 4);
    int* counts        = (int*)alloc((size_t)n * sizeof(int));
    int* offsets       = (int*)alloc((size_t)(n + 1) * sizeof(int));
    int* rank          = (int*)alloc((size_t)e * sizeof(int));
    int* bsums         = (int*)alloc((size_t)nb * sizeof(int));
    int* srcSorted     = (int*)alloc((size_t)e * sizeof(int));
    (void)ws_size; (void)n_in; (void)out_size;

    prep_all<<<24 + hB + zB, 256, 0, stream>>>(Wq, Wk, Wv, h, WTb, hb, counts, n, hB);
    hist_rank<<<(e + 255) / 256, 256, 0, stream>>>(dst, counts, rank, e);
    scan_block_sums<<<nb, 256, 0, stream>>>(counts, bsums, n);
    scan_final2<<<nb, 256, 0, stream>>>(counts, bsums, offsets, n, e);
    fill_kernel<<<(e + 255) / 256, 256, 0, stream>>>(src, dst, rank, offsets, srcSorted, e);
    qkv_gemm_mfma<<<nblk, 512, 0, stream>>>(hb, WTb, bq, bk, bv, Qb, Kb, Vb);
    mha_node<<<((size_t)n * 64 + 255) / 256, 256, 0, stream>>>(
        Qb, Kb, Vb, offsets, srcSorted, out, n);
}